// Round 8
// baseline (389.685 us; speedup 1.0000x reference)
//
#include <hip/hip_runtime.h>

#define DD 256
#define SS 256
#define BB 64
#define NEDGE 500000
#define MM 2048
#define NEG_INF -10000000000.0f
#define ROWF4 512          // float4 stride between (b,s) type rows in token_reprs
#define NROWS (BB * SS)    // 16384
#define EBLK 1954          // ceil(NEDGE/256)

// workspace byte offsets
#define OFF_VC     0
#define OFF_MSORT  2048
#define OFF_BSTART 10240
#define OFF_EBKT   11264            // 65 ints
#define OFF_CURS   12288            // 64 ints
#define OFF_EPAIR  (1 << 20)        // 500000 uint2 (scope,goal), bucket-sorted
#define OFF_EORIG  (6 << 20)        // 500000 uint original edge id
#define OFF_P2     (8 << 20)        // NROWS f16 rows of a      (512 B each)
#define OFF_QROW   (16 << 20)       // NROWS f16 rows of a*v
#define OFF_MROWS  (24 << 20)       // MM f16 mask rows

typedef _Float16 h2 __attribute__((ext_vector_type(2)));

__device__ __forceinline__ h2 uh(unsigned u) {
    union { unsigned x; h2 h; } c; c.x = u; return c.h;
}
__device__ __forceinline__ unsigned hpack(float a, float b) {
    union { h2 h; unsigned u; } c;
    c.h = h2{(_Float16)a, (_Float16)b};
    return c.u;
}

#if __has_builtin(__builtin_amdgcn_fdot2)
__device__ __forceinline__ float FDOT2(h2 a, h2 b, float c) {
    return __builtin_amdgcn_fdot2(a, b, c, false);
}
#else
__device__ __forceinline__ float FDOT2(h2 a, h2 b, float c) {
    return c + (float)a.x * (float)b.x + (float)a.y * (float)b.y;
}
#endif

__device__ __forceinline__ float dot16(uint4 a, uint4 b, float acc) {
    acc = FDOT2(uh(a.x), uh(b.x), acc);
    acc = FDOT2(uh(a.y), uh(b.y), acc);
    acc = FDOT2(uh(a.z), uh(b.z), acc);
    acc = FDOT2(uh(a.w), uh(b.w), acc);
    return acc;
}

// block 0: vc = w1@w2 (+bias); block 1: counting-sort m by batch;
// block 2: zero 64-bucket edge hist + cursors
__global__ void setup_k(const float* __restrict__ w1, const float* __restrict__ b1,
                        const float* __restrict__ w2, const float* __restrict__ b2,
                        const int* __restrict__ bp,
                        float* __restrict__ vc, int* __restrict__ msorted,
                        int* __restrict__ bstart, int* __restrict__ ebkt,
                        int* __restrict__ cursor) {
    const int t = threadIdx.x;
    if (blockIdx.x == 0) {
        float acc = 0.f;
        #pragma unroll 4
        for (int j = 0; j < DD / 2; ++j) acc += w1[t * (DD / 2) + j] * w2[j];
        vc[t] = acc;
        if (t == 0) {
            float c = b2[0];
            for (int j = 0; j < DD / 2; ++j) c += b1[j] * w2[j];
            vc[DD] = c;
        }
    } else if (blockIdx.x == 1) {
        __shared__ int h[BB];
        __shared__ int offs[BB + 1];
        if (t < BB) h[t] = 0;
        __syncthreads();
        for (int m = t; m < MM; m += 256) atomicAdd(&h[bp[m]], 1);
        __syncthreads();
        if (t == 0) {
            int acc = 0;
            for (int i = 0; i < BB; ++i) { offs[i] = acc; acc += h[i]; }
            offs[BB] = acc;
        }
        __syncthreads();
        if (t < BB + 1) bstart[t] = offs[t];
        __syncthreads();
        for (int m = t; m < MM; m += 256) {
            int pos = atomicAdd(&offs[bp[m]], 1);
            msorted[pos] = m;
        }
    } else {
        if (t < 65) ebkt[t] = 0;
        if (t < 64) cursor[t] = 0;
    }
}

// blocks [0,4096): type rows -> p2u (f16 a) + qrow (f16 a*v)
// blocks [4096,4608): mask rows -> mrows
// blocks [4608,4608+EBLK): 64-bucket (scope>>11, goal>>11) histogram
__global__ __launch_bounds__(256) void compact_hist(
        const float* __restrict__ tok, const int* __restrict__ lmi,
        const int* __restrict__ edges, const float* __restrict__ vc,
        unsigned* __restrict__ p2u, unsigned* __restrict__ qrow,
        unsigned* __restrict__ mru, int* __restrict__ ebkt) {
    const int t = threadIdx.x;
    const int lane = t & 63, w = t >> 6;
    const int bid = blockIdx.x;
    if (bid < NROWS / 4) {
        const int row = bid * 4 + w;
        const float4 a = ((const float4*)tok)[(size_t)row * ROWF4 + lane];
        const float4 v = ((const float4*)vc)[lane];
        ((uint2*)p2u)[(size_t)row * 64 + lane] =
            make_uint2(hpack(a.x, a.y), hpack(a.z, a.w));
        ((uint2*)qrow)[(size_t)row * 64 + lane] =
            make_uint2(hpack(a.x * v.x, a.y * v.y), hpack(a.z * v.z, a.w * v.w));
    } else if (bid < NROWS / 4 + MM / 4) {
        const int m = (bid - NROWS / 4) * 4 + w;
        const float4 a = ((const float4*)(tok + (size_t)lmi[m] * DD))[lane];
        ((uint2*)mru)[(size_t)m * 64 + lane] =
            make_uint2(hpack(a.x, a.y), hpack(a.z, a.w));
    } else {
        __shared__ int lh[64];
        if (t < 64) lh[t] = 0;
        __syncthreads();
        const int e = (bid - NROWS / 4 - MM / 4) * 256 + t;
        if (e < NEDGE) {
            const int sc = __builtin_nontemporal_load(edges + e);
            const int gl = __builtin_nontemporal_load(edges + NEDGE + e);
            atomicAdd(&lh[(sc >> 11) * 8 + (gl >> 11)], 1);
        }
        __syncthreads();
        if (t < 64 && lh[t]) atomicAdd(&ebkt[t], lh[t]);
    }
}

// exclusive prefix over 64 buckets
__global__ void prefix64(int* __restrict__ ebkt, int* __restrict__ cursor) {
    if (threadIdx.x == 0) {
        int acc = 0;
        for (int i = 0; i < 64; ++i) {
            int c = ebkt[i];
            ebkt[i] = acc; cursor[i] = acc;
            acc += c;
        }
        ebkt[64] = acc;
    }
}

// two-level scatter into bucket-sorted order (LDS hist -> one reservation
// per bucket per block -> LDS-ranked scatter)
__global__ __launch_bounds__(256) void scatter_k(
        const int* __restrict__ edges, int* __restrict__ cursor,
        uint2* __restrict__ epair, unsigned* __restrict__ eorig) {
    __shared__ int lh[64], lbase[64], lcur[64];
    const int t = threadIdx.x;
    if (t < 64) lh[t] = 0;
    __syncthreads();
    const int e = blockIdx.x * 256 + t;
    int sc = 0, gl = 0, bkt = 0;
    const bool v = e < NEDGE;
    if (v) {
        sc = __builtin_nontemporal_load(edges + e);
        gl = __builtin_nontemporal_load(edges + NEDGE + e);
        bkt = (sc >> 11) * 8 + (gl >> 11);
        atomicAdd(&lh[bkt], 1);
    }
    __syncthreads();
    if (t < 64) {
        lbase[t] = lh[t] ? atomicAdd(&cursor[t], lh[t]) : 0;
        lcur[t] = 0;
    }
    __syncthreads();
    if (v) {
        const int r = atomicAdd(&lcur[bkt], 1);
        const int pos = lbase[bkt] + r;
        epair[pos] = make_uint2((unsigned)sc, (unsigned)gl);
        eorig[pos] = (unsigned)e;
    }
}

// Latin-square XCD-partitioned edge dot. Block bid: XCD g=bid&7 (round-robin
// blockIdx->XCD mapping), worker w=bid>>3 of 64. Phase p processes bucket
// (p, (p+g)&7): per-XCD instantaneous footprint = scope slab p (1 MB of qrow)
// + goal slab (p+g)&7 (1 MB of p2u) -> L2-resident by construction. Static
// 1/64 split per bucket bounds drift; no barriers needed.
__global__ __launch_bounds__(256) void edge_xcd(
        const unsigned* __restrict__ qrow, const unsigned* __restrict__ p2u,
        const uint2* __restrict__ epair, const unsigned* __restrict__ eorig,
        const int* __restrict__ ebkt, const float* __restrict__ vc,
        float* __restrict__ out) {
    const int t = threadIdx.x;
    const int l32 = t & 31, grp = t >> 5;   // 8 edge-groups of 32 lanes
    const int g = blockIdx.x & 7;
    const int w = blockIdx.x >> 3;
    const float c = vc[DD];
    const uint4* Q = (const uint4*)qrow;
    const uint4* A = (const uint4*)p2u;
    #pragma unroll 1
    for (int p = 0; p < 8; ++p) {
        const int bkt = p * 8 + ((p + g) & 7);
        const int S = ebkt[bkt];
        const int L = ebkt[bkt + 1] - S;
        const int lo = S + (L * w >> 6);
        const int hi = S + (L * (w + 1) >> 6);
        for (int i = lo + grp; i < hi; i += 8) {
            const uint2 pr = epair[i];
            const uint4 qa = Q[(size_t)pr.x * 32 + l32];
            const uint4 ab = A[(size_t)pr.y * 32 + l32];
            float r = dot16(qa, ab, 0.f);
            r += __shfl_down(r, 16, 32);
            r += __shfl_down(r, 8, 32);
            r += __shfl_down(r, 4, 32);
            r += __shfl_down(r, 2, 32);
            r += __shfl_down(r, 1, 32);
            if (l32 == 0) out[eorig[i]] = r + c;
        }
    }
}

// lm GEMM: block=(batch, 64-col s-tile, 32-mask chunk); full tile staged once;
// 2x4 register tile; LDS row stride 33 uint4 (conflict-free).
__global__ __launch_bounds__(256) void lm_gemm(
        const unsigned* __restrict__ p2u,
        const unsigned* __restrict__ mru,
        const int* __restrict__ msorted,
        const int* __restrict__ bstart,
        const int* __restrict__ tpm,
        float* __restrict__ out) {
    const int b  = blockIdx.x;
    const int st = blockIdx.y;
    const int ch = blockIdx.z;
    const int s0 = bstart[b], nmt = bstart[b + 1] - s0;
    const int base = ch * 32;
    if (base >= nmt) return;
    const int nm = min(32, nmt - base);
    const int t = threadIdx.x;

    __shared__ uint4 candS[64 * 33];
    __shared__ uint4 maskS[32 * 33];
    __shared__ int mids[32];

    if (t < 32) mids[t] = msorted[s0 + base + min(t, nm - 1)];
    __syncthreads();
    for (int f = t; f < 32 * 32; f += 256) {
        const int r = f >> 5, q = f & 31;
        maskS[r * 33 + q] = ((const uint4*)mru)[(size_t)mids[r] * 32 + q];
    }
    for (int f = t; f < 64 * 32; f += 256) {
        const int r = f >> 5, q = f & 31;
        candS[r * 33 + q] = ((const uint4*)p2u)[((size_t)b * SS + st * 64 + r) * 32 + q];
    }
    __syncthreads();

    const int tmg = t & 15, tsg = t >> 4;
    float acc[2][4];
    #pragma unroll
    for (int im = 0; im < 2; ++im)
        #pragma unroll
        for (int ss = 0; ss < 4; ++ss) acc[im][ss] = 0.f;

    #pragma unroll 4
    for (int j = 0; j < 32; ++j) {
        const uint4 a0 = maskS[tmg * 33 + j];
        const uint4 a1 = maskS[(tmg + 16) * 33 + j];
        #pragma unroll
        for (int ss = 0; ss < 4; ++ss) {
            const uint4 bb = candS[(tsg * 4 + ss) * 33 + j];
            acc[0][ss] = dot16(a0, bb, acc[0][ss]);
            acc[1][ss] = dot16(a1, bb, acc[1][ss]);
        }
    }

    const int col0 = st * 64 + tsg * 4;
    float4 msk;
    msk.x = tpm[b * SS + col0] ? 1.f : 0.f;
    msk.y = tpm[b * SS + col0 + 1] ? 1.f : 0.f;
    msk.z = tpm[b * SS + col0 + 2] ? 1.f : 0.f;
    msk.w = tpm[b * SS + col0 + 3] ? 1.f : 0.f;
    #pragma unroll
    for (int im = 0; im < 2; ++im) {
        const int mi = tmg + im * 16;
        if (mi < nm) {
            float4 o;
            o.x = msk.x != 0.f ? acc[im][0] : NEG_INF;
            o.y = msk.y != 0.f ? acc[im][1] : NEG_INF;
            o.z = msk.z != 0.f ? acc[im][2] : NEG_INF;
            o.w = msk.w != 0.f ? acc[im][3] : NEG_INF;
            *(float4*)&out[(size_t)mids[mi] * SS + col0] = o;
        }
    }
}

extern "C" void kernel_launch(void* const* d_in, const int* in_sizes, int n_in,
                              void* d_out, int out_size, void* d_ws, size_t ws_size,
                              hipStream_t stream) {
    const float* tok = (const float*)d_in[0];
    const float* w1  = (const float*)d_in[1];
    const float* b1  = (const float*)d_in[2];
    const float* w2  = (const float*)d_in[3];
    const float* b2  = (const float*)d_in[4];
    const int* edges = (const int*)d_in[5];
    const int* lmi   = (const int*)d_in[6];
    const int* bp    = (const int*)d_in[7];
    const int* tpm   = (const int*)d_in[8];

    float* out_lemmas = (float*)d_out;
    float* out_lm     = (float*)d_out + NEDGE;

    char* ws = (char*)d_ws;
    float* vc       = (float*)(ws + OFF_VC);
    int* msorted    = (int*)(ws + OFF_MSORT);
    int* bstart     = (int*)(ws + OFF_BSTART);
    int* ebkt       = (int*)(ws + OFF_EBKT);
    int* cursor     = (int*)(ws + OFF_CURS);
    uint2* epair    = (uint2*)(ws + OFF_EPAIR);
    unsigned* eorig = (unsigned*)(ws + OFF_EORIG);
    unsigned* p2u   = (unsigned*)(ws + OFF_P2);
    unsigned* qrow  = (unsigned*)(ws + OFF_QROW);
    unsigned* mru   = (unsigned*)(ws + OFF_MROWS);

    setup_k<<<3, 256, 0, stream>>>(w1, b1, w2, b2, bp, vc, msorted, bstart,
                                   ebkt, cursor);
    compact_hist<<<NROWS / 4 + MM / 4 + EBLK, 256, 0, stream>>>(
        tok, lmi, edges, vc, p2u, qrow, mru, ebkt);
    prefix64<<<1, 64, 0, stream>>>(ebkt, cursor);
    scatter_k<<<EBLK, 256, 0, stream>>>(edges, cursor, epair, eorig);
    edge_xcd<<<512, 256, 0, stream>>>(qrow, p2u, epair, eorig, ebkt, vc, out_lemmas);
    lm_gemm<<<dim3(BB, 4, 4), 256, 0, stream>>>(p2u, mru, msorted, bstart, tpm, out_lm);
}